// Round 1
// baseline (708.109 us; speedup 1.0000x reference)
//
#include <hip/hip_runtime.h>

typedef unsigned short ushort_t;
typedef __bf16 bf16x8 __attribute__((ext_vector_type(8)));
typedef float f32x4 __attribute__((ext_vector_type(4)));

#define T_ 10
#define N_ 30000
#define F_ 256
#define H_ 128
#define L_ 5
#define YR_ 5
#define NSTEP 5
#define MROWS_ENC (T_*N_)      /* 300000 */
#define MROWS_GRU (YR_*N_)     /* 150000 */

/* ---- workspace layout (bytes) ---- */
#define OFF_EMB   ((size_t)0)
#define SZ_EMB    ((size_t)T_*N_*H_*2)          /* 76,800,000 */
#define OFF_WENC  (OFF_EMB + SZ_EMB)
#define SZ_WENC   ((size_t)F_*H_*2)             /* 65,536 */
#define OFF_WIH   (OFF_WENC + SZ_WENC)
#define SZ_W3H    ((size_t)H_*3*H_*2)           /* 98,304 */
#define OFF_WHH   (OFF_WIH + SZ_W3H)
#define OFF_ACC   (OFF_WHH + SZ_W3H)            /* 2 floats: [0]=l_time_sum, [1]=l_pred_sum */

/* ---- helpers ---- */
__device__ __forceinline__ unsigned int bfbits(float x){
    unsigned int u = __float_as_uint(x);
    return (u + 0x7fffu + ((u >> 16) & 1u)) >> 16;   /* RNE f32->bf16 */
}
__device__ __forceinline__ unsigned int pack2(float lo, float hi){
    return bfbits(lo) | (bfbits(hi) << 16);
}
__device__ __forceinline__ float b2f(ushort_t u){
    return __uint_as_float(((unsigned int)u) << 16);
}
__device__ __forceinline__ f32x4 mfma16(bf16x8 a, bf16x8 b, f32x4 c){
    return __builtin_amdgcn_mfma_f32_16x16x32_bf16(a, b, c, 0, 0, 0);
}
__device__ __forceinline__ float fexp2_(float x){ return __builtin_amdgcn_exp2f(x); }
__device__ __forceinline__ float frcp_(float x){ return __builtin_amdgcn_rcpf(x); }
__device__ __forceinline__ float sigm_(float x){ return frcp_(1.f + fexp2_(-1.44269504f*x)); }
__device__ __forceinline__ float tanhfast_(float x){ return 1.f - 2.f*frcp_(1.f + fexp2_(2.88539008f*x)); }
__device__ __forceinline__ float softplus_(float x){
    float ax = fabsf(x);
    return fmaxf(x, 0.f) + log1pf(fexp2_(-1.44269504f*ax));
}
__device__ __forceinline__ float wave_sum(float v){
#pragma unroll
    for (int o = 32; o > 0; o >>= 1) v += __shfl_down(v, o, 64);
    return v;
}

/* ---- prep: transpose+convert weights to bf16, zero accumulators ---- */
__global__ void prep_kernel(const float* __restrict__ We, const float* __restrict__ Wih,
                            const float* __restrict__ Whh,
                            ushort_t* __restrict__ Wet, ushort_t* __restrict__ Wiht,
                            ushort_t* __restrict__ Whht, float* __restrict__ accv)
{
    int i = blockIdx.x * 256 + threadIdx.x;
    if (i < 2) accv[i] = 0.f;
    if (i < F_*H_){                       /* Wet[h][f] = We[f][h] */
        int h = i >> 8, f = i & 255;
        Wet[i] = (ushort_t)bfbits(We[f*H_ + h]);
    }
    if (i < 3*H_*H_){                     /* W*t[c][k] = W[k][c] */
        int c = i >> 7, k = i & 127;
        Wiht[i] = (ushort_t)bfbits(Wih[k*(3*H_) + c]);
        Whht[i] = (ushort_t)bfbits(Whh[k*(3*H_) + c]);
    }
}

/* ---- encoder: emb = relu(X @ W_enc), bf16 out [T*N][128] ---- */
__global__ __launch_bounds__(256, 2) void enc_kernel(const float* __restrict__ X,
                                                     const ushort_t* __restrict__ Wet,
                                                     ushort_t* __restrict__ emb)
{
    __shared__ __attribute__((aligned(16))) ushort_t Xl[128*40];  /* [row][k] pitch 40 */
    __shared__ __attribute__((aligned(16))) ushort_t Wl[128*40];  /* [col][k] pitch 40 */
    const int tid = threadIdx.x;
    const int wv = tid >> 6, lane = tid & 63;
    const int m = lane & 15, q = lane >> 4;
    const int rowbase = blockIdx.x * 128;

    f32x4 acc[8][2];
#pragma unroll
    for (int a = 0; a < 8; ++a)
#pragma unroll
        for (int b = 0; b < 2; ++b)
            acc[a][b] = (f32x4){0.f, 0.f, 0.f, 0.f};

    const int srow = tid >> 1, shalf = tid & 1;
    int xrow = rowbase + srow; if (xrow > MROWS_ENC - 1) xrow = MROWS_ENC - 1;
    const float*    xp   = X   + (size_t)xrow * F_ + shalf * 16;
    const ushort_t* wp   = Wet + srow * F_ + shalf * 16;
    ushort_t*       xdst = &Xl[srow * 40 + shalf * 16];
    ushort_t*       wdst = &Wl[srow * 40 + shalf * 16];

    for (int ks = 0; ks < 8; ++ks){
        const float* xs = xp + ks * 32;
        float4 v0 = *(const float4*)(xs);
        float4 v1 = *(const float4*)(xs + 4);
        float4 v2 = *(const float4*)(xs + 8);
        float4 v3 = *(const float4*)(xs + 12);
        uint4 p0, p1;
        p0.x = pack2(v0.x, v0.y); p0.y = pack2(v0.z, v0.w);
        p0.z = pack2(v1.x, v1.y); p0.w = pack2(v1.z, v1.w);
        p1.x = pack2(v2.x, v2.y); p1.y = pack2(v2.z, v2.w);
        p1.z = pack2(v3.x, v3.y); p1.w = pack2(v3.z, v3.w);
        *(uint4*)xdst       = p0;
        *(uint4*)(xdst + 8) = p1;
        uint4 w0 = *(const uint4*)(wp + ks * 32);
        uint4 w1 = *(const uint4*)(wp + ks * 32 + 8);
        *(uint4*)wdst       = w0;
        *(uint4*)(wdst + 8) = w1;
        __syncthreads();

        bf16x8 af[8];
#pragma unroll
        for (int rt = 0; rt < 8; ++rt)
            af[rt] = *reinterpret_cast<const bf16x8*>(&Xl[(rt*16 + m)*40 + q*8]);
        bf16x8 b0 = *reinterpret_cast<const bf16x8*>(&Wl[(wv*32 +      m)*40 + q*8]);
        bf16x8 b1 = *reinterpret_cast<const bf16x8*>(&Wl[(wv*32 + 16 + m)*40 + q*8]);
#pragma unroll
        for (int rt = 0; rt < 8; ++rt){
            acc[rt][0] = mfma16(af[rt], b0, acc[rt][0]);
            acc[rt][1] = mfma16(af[rt], b1, acc[rt][1]);
        }
        __syncthreads();
    }

#pragma unroll
    for (int rt = 0; rt < 8; ++rt)
#pragma unroll
        for (int ct = 0; ct < 2; ++ct){
            const int col = wv*32 + ct*16 + m;
#pragma unroll
            for (int i = 0; i < 4; ++i){
                int row = rowbase + rt*16 + q*4 + i;
                if (row < MROWS_ENC){
                    float v = acc[rt][ct][i];
                    v = v > 0.f ? v : 0.f;
                    emb[(size_t)row * H_ + col] = (ushort_t)bfbits(v);
                }
            }
        }
}

/* ---- l_time: mean_n,t sum_h (emb[t]-emb[t+1])^2 ---- */
__global__ __launch_bounds__(256) void ltime_kernel(const ushort_t* __restrict__ emb,
                                                    float* __restrict__ accv)
{
    const int g = blockIdx.x * 256 + threadIdx.x;   /* 480000 = 30000*16 chunks of 8 */
    const int base = g * 8;
    float s = 0.f;
    uint4 pv = *(const uint4*)(emb + base);
#pragma unroll
    for (int t = 1; t < T_; ++t){
        uint4 cv = *(const uint4*)(emb + (size_t)t * N_ * H_ + base);
        const unsigned int pa[4] = {pv.x, pv.y, pv.z, pv.w};
        const unsigned int ca[4] = {cv.x, cv.y, cv.z, cv.w};
#pragma unroll
        for (int j = 0; j < 4; ++j){
            float al = __uint_as_float(pa[j] << 16), ah = __uint_as_float(pa[j] & 0xffff0000u);
            float bl = __uint_as_float(ca[j] << 16), bh = __uint_as_float(ca[j] & 0xffff0000u);
            float d0 = al - bl, d1 = ah - bh;
            s += d0*d0 + d1*d1;
        }
        pv = cv;
    }
    s = wave_sum(s);
    __shared__ float red[4];
    const int lane = threadIdx.x & 63, wv = threadIdx.x >> 6;
    if (lane == 0) red[wv] = s;
    __syncthreads();
    if (threadIdx.x == 0) atomicAdd(&accv[0], red[0] + red[1] + red[2] + red[3]);
}

/* ---- GRU + heads + prediction loss ---- */
__global__ __launch_bounds__(512, 2) void gru_kernel(const ushort_t* __restrict__ emb,
                                                     const ushort_t* __restrict__ Wiht,
                                                     const ushort_t* __restrict__ Whht,
                                                     const float* __restrict__ bih,
                                                     const float* __restrict__ bhh,
                                                     const float* __restrict__ Wheads,
                                                     const float* __restrict__ bheads,
                                                     const float* __restrict__ Yv,
                                                     const int* __restrict__ years,
                                                     float* __restrict__ accv)
{
    __shared__ __attribute__((aligned(16))) ushort_t Al[64*136];  /* [row][k] pitch 136 */
    __shared__ float Whl[3*H_];
    __shared__ float red[8];
    const int tid = threadIdx.x;
    const int wv = tid >> 6, lane = tid & 63;
    const int m = lane & 15, q = lane >> 4;
    const int rowbase = blockIdx.x * 64;

    if (tid < 3*H_) Whl[tid] = Wheads[tid];

    /* per-lane gate biases (column = g*128 + wv*16 + m) */
    const int cb = wv*16 + m;
    const float bi0 = bih[cb], bi1 = bih[128 + cb], bi2 = bih[256 + cb];
    const float bh0 = bhh[cb], bh1 = bhh[128 + cb], bh2 = bhh[256 + cb];

    /* W_ih fragments in registers: wave owns cols [16*wv,16*wv+16) of each gate */
    bf16x8 wf[3][4];
#pragma unroll
    for (int g = 0; g < 3; ++g)
#pragma unroll
        for (int ks = 0; ks < 4; ++ks)
            wf[g][ks] = *reinterpret_cast<const bf16x8*>(
                Wiht + (size_t)(g*128 + cb)*H_ + ks*32 + q*8);

    /* stage v tile (gathered rows of emb) into Al */
#pragma unroll
    for (int rep = 0; rep < 2; ++rep){
        int ci = rep*512 + tid;
        int r = ci >> 4, ch = ci & 15;
        int gr = rowbase + r; if (gr > MROWS_GRU - 1) gr = MROWS_GRU - 1;
        int yy = gr / N_;
        int n  = gr - yy * N_;
        int yr = years[yy];
        uint4 d = *(const uint4*)(emb + ((size_t)(yr*N_ + n))*H_ + ch*8);
        *(uint4*)&Al[r*136 + ch*8] = d;
    }
    __syncthreads();

    /* gx = v @ W_ih + b_ih */
    f32x4 gx[4][3];
#pragma unroll
    for (int rt = 0; rt < 4; ++rt)
#pragma unroll
        for (int g = 0; g < 3; ++g)
            gx[rt][g] = (f32x4){0.f, 0.f, 0.f, 0.f};
#pragma unroll
    for (int ks = 0; ks < 4; ++ks){
        bf16x8 a[4];
#pragma unroll
        for (int rt = 0; rt < 4; ++rt)
            a[rt] = *reinterpret_cast<const bf16x8*>(&Al[(rt*16 + m)*136 + ks*32 + q*8]);
#pragma unroll
        for (int rt = 0; rt < 4; ++rt)
#pragma unroll
            for (int g = 0; g < 3; ++g)
                gx[rt][g] = mfma16(a[rt], wf[g][ks], gx[rt][g]);
    }
#pragma unroll
    for (int rt = 0; rt < 4; ++rt)
#pragma unroll
        for (int i = 0; i < 4; ++i){
            gx[rt][0][i] += bi0; gx[rt][1][i] += bi1; gx[rt][2][i] += bi2;
        }

    /* swap register weights to W_hh */
#pragma unroll
    for (int g = 0; g < 3; ++g)
#pragma unroll
        for (int ks = 0; ks < 4; ++ks)
            wf[g][ks] = *reinterpret_cast<const bf16x8*>(
                Whht + (size_t)(g*128 + cb)*H_ + ks*32 + q*8);

    f32x4 h[4];
#pragma unroll
    for (int rt = 0; rt < 4; ++rt) h[rt] = (f32x4){0.f, 0.f, 0.f, 0.f};

#pragma unroll 1
    for (int step = 0; step < NSTEP; ++step){
        f32x4 gh[4][3];
#pragma unroll
        for (int rt = 0; rt < 4; ++rt)
#pragma unroll
            for (int g = 0; g < 3; ++g)
                gh[rt][g] = (f32x4){0.f, 0.f, 0.f, 0.f};
        if (step > 0){
            __syncthreads();   /* previous Al reads done */
#pragma unroll
            for (int rt = 0; rt < 4; ++rt)
#pragma unroll
                for (int i = 0; i < 4; ++i)
                    Al[(rt*16 + q*4 + i)*136 + cb] = (ushort_t)bfbits(h[rt][i]);
            __syncthreads();
#pragma unroll
            for (int ks = 0; ks < 4; ++ks){
                bf16x8 a[4];
#pragma unroll
                for (int rt = 0; rt < 4; ++rt)
                    a[rt] = *reinterpret_cast<const bf16x8*>(&Al[(rt*16 + m)*136 + ks*32 + q*8]);
#pragma unroll
                for (int rt = 0; rt < 4; ++rt)
#pragma unroll
                    for (int g = 0; g < 3; ++g)
                        gh[rt][g] = mfma16(a[rt], wf[g][ks], gh[rt][g]);
            }
        }
#pragma unroll
        for (int rt = 0; rt < 4; ++rt)
#pragma unroll
            for (int i = 0; i < 4; ++i){
                float r_ = sigm_(gx[rt][0][i] + gh[rt][0][i] + bh0);
                float z_ = sigm_(gx[rt][1][i] + gh[rt][1][i] + bh1);
                float n_ = tanhfast_(gx[rt][2][i] + r_ * (gh[rt][2][i] + bh2));
                h[rt][i] = (1.f - z_) * n_ + z_ * h[rt][i];
            }
    }

    /* write h_last to Al for the heads phase */
    __syncthreads();
#pragma unroll
    for (int rt = 0; rt < 4; ++rt)
#pragma unroll
        for (int i = 0; i < 4; ++i)
            Al[(rt*16 + q*4 + i)*136 + cb] = (ushort_t)bfbits(h[rt][i]);
    __syncthreads();

    /* heads + log-normal loss: 8 threads per row */
    float loss = 0.f;
    {
        const int r = tid >> 3, part = tid & 7;
        float a0 = 0.f, a1 = 0.f, a2 = 0.f;
#pragma unroll
        for (int kk = 0; kk < 16; ++kk){
            int k = part*16 + kk;
            float hv = b2f(Al[r*136 + k]);
            a0 += hv * Whl[k*3 + 0];
            a1 += hv * Whl[k*3 + 1];
            a2 += hv * Whl[k*3 + 2];
        }
#pragma unroll
        for (int o = 4; o > 0; o >>= 1){
            a0 += __shfl_down(a0, o, 64);
            a1 += __shfl_down(a1, o, 64);
            a2 += __shfl_down(a2, o, 64);
        }
        const int gr = rowbase + r;
        if (part == 0 && gr < MROWS_GRU){
            int yy = gr / N_;
            int n  = gr - yy * N_;
            int yr = years[yy];
            float eta = softplus_(a0 + bheads[0]);
            float mu  = a1 + bheads[1];
            float sg  = softplus_(a2 + bheads[2]) + 1e-3f;
            float inv = frcp_(sg);
            const float LH[5] = {0.f, 0.69314718f, 1.09861229f, 1.38629436f, 1.60943791f};
            const float* yrow = Yv + ((size_t)(yr*N_ + n)) * L_;
            float prev = 0.f;
#pragma unroll
            for (int l = 0; l < L_; ++l){
                float zz  = (LH[l] - mu) * inv;
                float cdf = 0.5f * erfcf(-zz * 0.70710678f);
                float yc  = eta * cdf;
                float yh  = yc - prev; prev = yc;
                float d   = log1pf(yrow[l] + 1.0f) - log1pf(yh);
                loss += d * d;
            }
        }
    }
    loss = wave_sum(loss);
    if (lane == 0) red[wv] = loss;
    __syncthreads();
    if (tid == 0){
        float t = 0.f;
#pragma unroll
        for (int w2 = 0; w2 < 8; ++w2) t += red[w2];
        atomicAdd(&accv[1], t);
    }
}

/* ---- finalize ---- */
__global__ void fin_kernel(const float* __restrict__ accv, float* __restrict__ out)
{
    out[0] = accv[1] * (1.f / (float)(YR_*N_*L_)) +
             1e-3f * accv[0] * (1.f / (float)((T_-1)*N_));
}

extern "C" void kernel_launch(void* const* d_in, const int* in_sizes, int n_in,
                              void* d_out, int out_size, void* d_ws, size_t ws_size,
                              hipStream_t stream)
{
    (void)in_sizes; (void)n_in; (void)out_size; (void)ws_size;
    const float* X       = (const float*)d_in[0];
    const float* W_enc   = (const float*)d_in[1];
    const float* W_ih    = (const float*)d_in[2];
    const float* W_hh    = (const float*)d_in[3];
    const float* b_ih    = (const float*)d_in[4];
    const float* b_hh    = (const float*)d_in[5];
    const float* W_heads = (const float*)d_in[6];
    const float* b_heads = (const float*)d_in[7];
    const float* Yv      = (const float*)d_in[8];
    const int*   years   = (const int*)d_in[9];

    char* ws = (char*)d_ws;
    ushort_t* emb  = (ushort_t*)(ws + OFF_EMB);
    ushort_t* Wet  = (ushort_t*)(ws + OFF_WENC);
    ushort_t* Wiht = (ushort_t*)(ws + OFF_WIH);
    ushort_t* Whht = (ushort_t*)(ws + OFF_WHH);
    float*    accv = (float*)(ws + OFF_ACC);

    prep_kernel<<<192, 256, 0, stream>>>(W_enc, W_ih, W_hh, Wet, Wiht, Whht, accv);
    enc_kernel<<<(MROWS_ENC + 127)/128, 256, 0, stream>>>(X, Wet, emb);
    ltime_kernel<<<(N_*16)/256, 256, 0, stream>>>(emb, accv);
    gru_kernel<<<(MROWS_GRU + 63)/64, 512, 0, stream>>>(emb, Wiht, Whht, b_ih, b_hh,
                                                        W_heads, b_heads, Yv, years, accv);
    fin_kernel<<<1, 1, 0, stream>>>(accv, (float*)d_out);
}